// Round 3
// baseline (553.224 us; speedup 1.0000x reference)
//
#include <hip/hip_runtime.h>
#include <hip/hip_bf16.h>
#include <stdint.h>

#define T_SEQ 8192
#define B_SZ 2
#define CDIM 1024
#define NH 16
#define HDIM 64
#define NW 32

typedef unsigned short ushort_t;
typedef __attribute__((ext_vector_type(8))) short short8;     // 8 bf16 (4 VGPRs) MFMA A/B frag
typedef __attribute__((ext_vector_type(8))) unsigned short us8;
typedef __attribute__((ext_vector_type(4))) float f32x4;      // MFMA C/D frag

__device__ __forceinline__ float bf2f(unsigned short h) {
  union { unsigned int u; float f; } c; c.u = ((unsigned int)h) << 16; return c.f;
}
__device__ __forceinline__ unsigned short f2bf(float f) {
  union { float f; unsigned int u; } c; c.f = f;
  return (unsigned short)((c.u + 0x7FFFu + ((c.u >> 16) & 1u)) >> 16);
}
__device__ __forceinline__ void gld16(void* lds, const void* g) {
  __builtin_amdgcn_global_load_lds(
      (const __attribute__((address_space(1))) void*)g,
      (__attribute__((address_space(3))) void*)lds, 16, 0, 0);
}

// ---------------- fp32 -> bf16 conversion (RTNE), 4 elems/thread ----------------
__global__ __launch_bounds__(256) void cvt_f32_bf16(const float* __restrict__ src,
                                                    ushort_t* __restrict__ dst, int n4)
{
  int i = blockIdx.x * 256 + threadIdx.x;
  if (i < n4) {
    float4 v = ((const float4*)src)[i];
    ushort4 o;
    o.x = f2bf(v.x); o.y = f2bf(v.y); o.z = f2bf(v.z); o.w = f2bf(v.w);
    ((ushort4*)dst)[i] = o;
  }
}

// ---------------- GEMM: Out[M,N] = A[M,K] @ W[N,K]^T + bias, bf16 in, bf16/fp32 out ----------------
template <bool OUTF32>
__global__ __launch_bounds__(256) void gemm_bt(const ushort_t* __restrict__ A,
                                               const ushort_t* __restrict__ W,
                                               const float* __restrict__ bias,
                                               void* __restrict__ OutP)
{
  __shared__ ushort_t As[128 * 32];
  __shared__ ushort_t Bs[128 * 32];
  const int t = threadIdx.x;
  const int lane = t & 63;
  const int wv = t >> 6;
  const int m0 = blockIdx.y * 128;
  const int n0 = blockIdx.x * 128;
  const int wm = (wv >> 1) * 64;
  const int wn = (wv & 1) * 64;

  f32x4 acc[4][4];
#pragma unroll
  for (int i = 0; i < 4; i++)
#pragma unroll
    for (int j = 0; j < 4; j++) acc[i][j] = (f32x4){0.f, 0.f, 0.f, 0.f};

  const int srow = t >> 2;
  const int scol = (t & 3) * 8;
  const ushort_t* Ag0 = A + (size_t)(m0 + srow) * CDIM + scol;
  const ushort_t* Ag1 = Ag0 + (size_t)64 * CDIM;
  const ushort_t* Wg0 = W + (size_t)(n0 + srow) * CDIM + scol;
  const ushort_t* Wg1 = Wg0 + (size_t)64 * CDIM;
  ushort_t* la0 = &As[srow * 32 + scol];
  ushort_t* la1 = &As[(srow + 64) * 32 + scol];
  ushort_t* lb0 = &Bs[srow * 32 + scol];
  ushort_t* lb1 = &Bs[(srow + 64) * 32 + scol];

  const int fr = lane & 15;
  const int kq = (lane >> 4) * 8;

  for (int kt = 0; kt < CDIM; kt += 32) {
    __syncthreads();
    gld16(la0, Ag0 + kt);
    gld16(la1, Ag1 + kt);
    gld16(lb0, Wg0 + kt);
    gld16(lb1, Wg1 + kt);
    __syncthreads();
    short8 a[4], b[4];
#pragma unroll
    for (int i = 0; i < 4; i++) a[i] = *(const short8*)&As[(wm + i * 16 + fr) * 32 + kq];
#pragma unroll
    for (int i = 0; i < 4; i++) b[i] = *(const short8*)&Bs[(wn + i * 16 + fr) * 32 + kq];
#pragma unroll
    for (int i = 0; i < 4; i++)
#pragma unroll
      for (int j = 0; j < 4; j++)
        acc[i][j] = __builtin_amdgcn_mfma_f32_16x16x32_bf16(a[i], b[j], acc[i][j], 0, 0, 0);
  }

  const int quad = lane >> 4;
#pragma unroll
  for (int j = 0; j < 4; j++) {
    int n = n0 + wn + j * 16 + fr;
    float bvv = bias[n];
#pragma unroll
    for (int i = 0; i < 4; i++) {
      int m = m0 + wm + i * 16 + quad * 4;
#pragma unroll
      for (int r = 0; r < 4; r++) {
        if constexpr (OUTF32)
          ((float*)OutP)[(size_t)(m + r) * CDIM + n] = acc[i][j][r] + bvv;
        else
          ((ushort_t*)OutP)[(size_t)(m + r) * CDIM + n] = f2bf(acc[i][j][r] + bvv);
      }
    }
  }
}

// ---------------- RoPE in-place on Q and K (bf16), cos/sin fp32 ----------------
__global__ __launch_bounds__(256) void rope_kernel(ushort_t* __restrict__ Q,
                                                   ushort_t* __restrict__ K,
                                                   const float* __restrict__ cosT,
                                                   const float* __restrict__ sinT)
{
  int idx = blockIdx.x * 256 + threadIdx.x;  // B*T*NH*4 threads
  int dg = idx & 3;
  int h = (idx >> 2) & 15;
  long bt = idx >> 6;            // 0..16383
  int tpos = (int)(bt & (T_SEQ - 1));
  int d0 = dg * 8;               // 0,8,16,24  (pairs (d, d+32); cos[t,d]==cos[t,d+32])
  size_t base = (size_t)bt * CDIM + h * HDIM;

  float4 c0 = *(const float4*)&cosT[(size_t)tpos * HDIM + d0];
  float4 c1 = *(const float4*)&cosT[(size_t)tpos * HDIM + d0 + 4];
  float4 s0 = *(const float4*)&sinT[(size_t)tpos * HDIM + d0];
  float4 s1 = *(const float4*)&sinT[(size_t)tpos * HDIM + d0 + 4];
  float cv[8] = {c0.x, c0.y, c0.z, c0.w, c1.x, c1.y, c1.z, c1.w};
  float sv[8] = {s0.x, s0.y, s0.z, s0.w, s1.x, s1.y, s1.z, s1.w};

#pragma unroll
  for (int which = 0; which < 2; which++) {
    ushort_t* P = which ? K : Q;
    us8 lo = *(const us8*)&P[base + d0];
    us8 hi = *(const us8*)&P[base + 32 + d0];
    us8 rlo, rhi;
#pragma unroll
    for (int i = 0; i < 8; i++) {
      float c = cv[i], s = sv[i];
      float l = bf2f(lo[i]), hh = bf2f(hi[i]);
      rlo[i] = f2bf(l * c - hh * s);
      rhi[i] = f2bf(hh * c + l * s);
    }
    *(us8*)&P[base + d0] = rlo;
    *(us8*)&P[base + 32 + d0] = rhi;
  }
}

// ---------------- windowed attention, flash-style over 8 chunks of 64 keys ----------------
// block: x=head(16), y=w*2+qhalf(64), z=batch(2); 256 threads, wave wv owns q-rows [wv*32, wv*32+32)
// NOTE: AO may alias Q — each block reads exactly the Q elements it later overwrites
// (Q staged to LDS before the first barrier; AO stored after the last; barriers order it).
__global__ __launch_bounds__(256) void attn_kernel(const ushort_t* __restrict__ Q,
                                                   const ushort_t* __restrict__ Kg,
                                                   const ushort_t* __restrict__ Vg,
                                                   const int* __restrict__ mask,
                                                   ushort_t* __restrict__ AO)
{
  __shared__ ushort_t Qs[128 * 72];
  __shared__ ushort_t Ks[64 * 72];
  __shared__ ushort_t Vts[64 * 72];   // transposed: [dim][key]
  __shared__ ushort_t Ps[128 * 72];
  __shared__ unsigned char att[512];

  const int t = threadIdx.x;
  const int lane = t & 63;
  const int wv = t >> 6;
  const int h = blockIdx.x;
  const int w = blockIdx.y >> 1;
  const int qh = blockIdx.y & 1;
  const int b = blockIdx.z;

  // attend flags for the window's 512 keys (key j -> pos w*256 + j - 128; pad attends)
  bool a0, a1;
  {
    int p0 = w * 256 + t - 128;
    a0 = (p0 < 0 || p0 >= T_SEQ) ? true : (mask[b * T_SEQ + p0] == 0);
    int p1 = p0 + 256;
    a1 = (p1 < 0 || p1 >= T_SEQ) ? true : (mask[b * T_SEQ + p1] == 0);
  }
  int all1 = __syncthreads_and((int)(a0 && a1));
  att[t] = a0 ? 1 : 0;
  att[t + 256] = a1 ? 1 : 0;
  if (all1 && t == 0) att[0] = 0;   // reference quirk: fully-attendable row masks key 0

  // stage Q tile [128][64] -> Qs (padded stride 72)
  {
    int row = t >> 3;
    int c8 = (t & 7) * 8;
    size_t qbase = ((size_t)b * T_SEQ + w * 256 + qh * 128) * CDIM + h * HDIM + c8;
#pragma unroll
    for (int p = 0; p < 4; p++) {
      int r = p * 32 + row;
      *(us8*)&Qs[r * 72 + c8] = *(const us8*)&Q[qbase + (size_t)r * CDIM];
    }
  }

  const int fr = lane & 15;
  const int quad = lane >> 4;
  const int kq = quad * 8;

  float m_run[2][4], l_run[2][4];
  f32x4 o[2][4];
#pragma unroll
  for (int mt = 0; mt < 2; mt++)
#pragma unroll
    for (int r = 0; r < 4; r++) { m_run[mt][r] = -3.0e38f; l_run[mt][r] = 0.f; }
#pragma unroll
  for (int mt = 0; mt < 2; mt++)
#pragma unroll
    for (int nt = 0; nt < 4; nt++) o[mt][nt] = (f32x4){0.f, 0.f, 0.f, 0.f};

  for (int kc = 0; kc < 8; kc++) {
    __syncthreads();  // prior chunk's LDS reads done (first iter: also covers Qs/att staging)
    // stage K chunk [64][64] and V chunk transposed [64dims][64keys]
    {
      int row = t >> 3;
      int c8 = (t & 7) * 8;
#pragma unroll
      for (int p = 0; p < 2; p++) {
        int jj = p * 32 + row;
        int pos = w * 256 + kc * 64 + jj - 128;
        us8 kval = (us8)(0), vval = (us8)(0);
        if (pos >= 0 && pos < T_SEQ) {
          size_t g = ((size_t)b * T_SEQ + pos) * CDIM + h * HDIM + c8;
          kval = *(const us8*)&Kg[g];
          vval = *(const us8*)&Vg[g];
        }
        *(us8*)&Ks[jj * 72 + c8] = kval;
#pragma unroll
        for (int i = 0; i < 8; i++) Vts[(c8 + i) * 72 + jj] = vval[i];
      }
    }
    __syncthreads();

    // S = Q K^T for this wave's 32 rows x 64 chunk keys
    short8 afr[2][2], bfr[4][2];
#pragma unroll
    for (int mt = 0; mt < 2; mt++)
#pragma unroll
      for (int ks = 0; ks < 2; ks++)
        afr[mt][ks] = *(const short8*)&Qs[(wv * 32 + mt * 16 + fr) * 72 + ks * 32 + kq];
#pragma unroll
    for (int nt = 0; nt < 4; nt++)
#pragma unroll
      for (int ks = 0; ks < 2; ks++)
        bfr[nt][ks] = *(const short8*)&Ks[(nt * 16 + fr) * 72 + ks * 32 + kq];

    f32x4 s[2][4];
#pragma unroll
    for (int mt = 0; mt < 2; mt++)
#pragma unroll
      for (int nt = 0; nt < 4; nt++) {
        f32x4 a = (f32x4){0.f, 0.f, 0.f, 0.f};
        a = __builtin_amdgcn_mfma_f32_16x16x32_bf16(afr[mt][0], bfr[nt][0], a, 0, 0, 0);
        a = __builtin_amdgcn_mfma_f32_16x16x32_bf16(afr[mt][1], bfr[nt][1], a, 0, 0, 0);
        s[mt][nt] = a;
      }

    // scale + mask
    bool at[4];
#pragma unroll
    for (int nt = 0; nt < 4; nt++) at[nt] = att[kc * 64 + nt * 16 + fr] != 0;
#pragma unroll
    for (int mt = 0; mt < 2; mt++)
#pragma unroll
      for (int nt = 0; nt < 4; nt++)
#pragma unroll
        for (int r = 0; r < 4; r++)
          s[mt][nt][r] = at[nt] ? s[mt][nt][r] * 0.125f : -3.0e38f;

    // online softmax (rows live in 16-lane groups: shfl_xor 1..8 stays in-group)
#pragma unroll
    for (int mt = 0; mt < 2; mt++) {
#pragma unroll
      for (int r = 0; r < 4; r++) {
        float mm = fmaxf(fmaxf(s[mt][0][r], s[mt][1][r]), fmaxf(s[mt][2][r], s[mt][3][r]));
        for (int off = 1; off < 16; off <<= 1) mm = fmaxf(mm, __shfl_xor(mm, off, 64));
        float mnew = fmaxf(m_run[mt][r], mm);
        float alpha = __expf(m_run[mt][r] - mnew);
        float rs = 0.f;
#pragma unroll
        for (int nt = 0; nt < 4; nt++) {
          float p = __expf(s[mt][nt][r] - mnew);
          s[mt][nt][r] = p;
          rs += p;
        }
        for (int off = 1; off < 16; off <<= 1) rs += __shfl_xor(rs, off, 64);
        l_run[mt][r] = l_run[mt][r] * alpha + rs;
        m_run[mt][r] = mnew;
#pragma unroll
        for (int nt = 0; nt < 4; nt++) o[mt][nt][r] *= alpha;
      }
    }

    // P (C-layout) -> LDS -> A-layout bf16
#pragma unroll
    for (int mt = 0; mt < 2; mt++)
#pragma unroll
      for (int nt = 0; nt < 4; nt++) {
        int row = wv * 32 + mt * 16 + quad * 4;
        int col = nt * 16 + fr;
#pragma unroll
        for (int r = 0; r < 4; r++) Ps[(row + r) * 72 + col] = f2bf(s[mt][nt][r]);
      }
    __syncthreads();  // order Ps writes vs reads (conservative)

    // O += P @ V
    short8 pf[2][2], vf[4][2];
#pragma unroll
    for (int mt = 0; mt < 2; mt++)
#pragma unroll
      for (int ks = 0; ks < 2; ks++)
        pf[mt][ks] = *(const short8*)&Ps[(wv * 32 + mt * 16 + fr) * 72 + ks * 32 + kq];
#pragma unroll
    for (int nt = 0; nt < 4; nt++)
#pragma unroll
      for (int ks = 0; ks < 2; ks++)
        vf[nt][ks] = *(const short8*)&Vts[(nt * 16 + fr) * 72 + ks * 32 + kq];
#pragma unroll
    for (int mt = 0; mt < 2; mt++)
#pragma unroll
      for (int nt = 0; nt < 4; nt++) {
        o[mt][nt] = __builtin_amdgcn_mfma_f32_16x16x32_bf16(pf[mt][0], vf[nt][0], o[mt][nt], 0, 0, 0);
        o[mt][nt] = __builtin_amdgcn_mfma_f32_16x16x32_bf16(pf[mt][1], vf[nt][1], o[mt][nt], 0, 0, 0);
      }
  }

  // normalize + store
  size_t obase = ((size_t)b * T_SEQ + w * 256 + qh * 128) * CDIM + h * HDIM;
#pragma unroll
  for (int mt = 0; mt < 2; mt++)
#pragma unroll
    for (int r = 0; r < 4; r++) {
      int row = wv * 32 + mt * 16 + quad * 4 + r;
      float inv = 1.0f / fmaxf(l_run[mt][r], 1e-30f);
#pragma unroll
      for (int nt = 0; nt < 4; nt++) {
        int col = nt * 16 + fr;
        AO[obase + (size_t)row * CDIM + col] = f2bf(o[mt][nt][r] * inv);
      }
    }
}

extern "C" void kernel_launch(void* const* d_in, const int* in_sizes, int n_in,
                              void* d_out, int out_size, void* d_ws, size_t ws_size,
                              hipStream_t stream)
{
  const float* x    = (const float*)d_in[0];
  const int*   pm   = (const int*)d_in[1];
  const float* cosT = (const float*)d_in[2];
  const float* sinT = (const float*)d_in[3];
  const float* Wq   = (const float*)d_in[4];
  const float* bq   = (const float*)d_in[5];
  const float* Wk   = (const float*)d_in[6];
  const float* bk   = (const float*)d_in[7];
  const float* Wv   = (const float*)d_in[8];
  const float* bv   = (const float*)d_in[9];
  const float* Wo   = (const float*)d_in[10];
  const float* bo   = (const float*)d_in[11];
  float* out = (float*)d_out;   // fp32 output, 67.1 MB

  // bf16 scratch layout:
  //   d_out lower half : K (bf16, 33.5 MB)   — dead before final GEMM overwrites d_out
  //   d_out upper half : x_bf (bf16, 33.5 MB) — dead after V projection
  //   ws: Wq/Wk/Wv/Wo bf16 (4 x 2 MB) + Q (33.5) + V (33.5)  = 75.5 MB
  const size_t NTOK = (size_t)B_SZ * T_SEQ;          // 16384
  const size_t NELT = NTOK * CDIM;                   // 16,777,216
  ushort_t* Kb  = (ushort_t*)d_out;
  ushort_t* xbf = (ushort_t*)d_out + NELT;           // upper half of d_out
  char* ws = (char*)d_ws;
  ushort_t* Wbf[4];
  for (int i = 0; i < 4; i++) Wbf[i] = (ushort_t*)(ws + (size_t)i * CDIM * CDIM * 2);
  ushort_t* Qb = (ushort_t*)(ws + 4 * (size_t)CDIM * CDIM * 2);
  ushort_t* Vb = Qb + NELT;
  ushort_t* AO = Qb;             // AO aliases Q (safe; see attn_kernel note)

  // fp32 -> bf16 conversions
  cvt_f32_bf16<<<(int)(NELT / 4 / 256), 256, 0, stream>>>(x, xbf, (int)(NELT / 4));
  const int wn4 = CDIM * CDIM / 4;
  cvt_f32_bf16<<<wn4 / 256, 256, 0, stream>>>(Wq, Wbf[0], wn4);
  cvt_f32_bf16<<<wn4 / 256, 256, 0, stream>>>(Wk, Wbf[1], wn4);
  cvt_f32_bf16<<<wn4 / 256, 256, 0, stream>>>(Wv, Wbf[2], wn4);
  cvt_f32_bf16<<<wn4 / 256, 256, 0, stream>>>(Wo, Wbf[3], wn4);

  dim3 gg(CDIM / 128, (int)(NTOK / 128));  // (8,128)
  gemm_bt<false><<<gg, 256, 0, stream>>>(xbf, Wbf[0], bq, Qb);
  gemm_bt<false><<<gg, 256, 0, stream>>>(xbf, Wbf[1], bk, Kb);
  gemm_bt<false><<<gg, 256, 0, stream>>>(xbf, Wbf[2], bv, Vb);

  rope_kernel<<<(int)(NTOK * NH * 4 / 256), 256, 0, stream>>>(Qb, Kb, cosT, sinT);

  attn_kernel<<<dim3(NH, NW * 2, B_SZ), 256, 0, stream>>>(Qb, Kb, Vb, pm, AO);

  gemm_bt<true><<<gg, 256, 0, stream>>>(AO, Wbf[3], bo, out);
}

// Round 4
// 485.879 us; speedup vs baseline: 1.1386x; 1.1386x over previous
//
#include <hip/hip_runtime.h>
#include <hip/hip_bf16.h>
#include <stdint.h>

#define T_SEQ 8192
#define B_SZ 2
#define CDIM 1024
#define NH 16
#define HDIM 64
#define NW 32

typedef unsigned short ushort_t;
typedef __attribute__((ext_vector_type(8))) short short8;     // 8 bf16 (4 VGPRs) MFMA A/B frag
typedef __attribute__((ext_vector_type(8))) unsigned short us8;
typedef __attribute__((ext_vector_type(4))) unsigned short us4;
typedef __attribute__((ext_vector_type(4))) float f32x4;      // MFMA C/D frag

__device__ __forceinline__ unsigned short f2bf(float f) {
  union { float f; unsigned int u; } c; c.f = f;
  return (unsigned short)((c.u + 0x7FFFu + ((c.u >> 16) & 1u)) >> 16);
}
__device__ __forceinline__ void gld16(void* lds, const void* g) {
  __builtin_amdgcn_global_load_lds(
      (const __attribute__((address_space(1))) void*)g,
      (__attribute__((address_space(3))) void*)lds, 16, 0, 0);
}

// ---------------- fp32 -> bf16 conversion (RTNE) ----------------
__global__ __launch_bounds__(256) void cvt_f32_bf16(const float* __restrict__ src,
                                                    ushort_t* __restrict__ dst, int n4)
{
  int i = blockIdx.x * 256 + threadIdx.x;
  if (i < n4) {
    float4 v = ((const float4*)src)[i];
    ushort4 o;
    o.x = f2bf(v.x); o.y = f2bf(v.y); o.z = f2bf(v.z); o.w = f2bf(v.w);
    ((ushort4*)dst)[i] = o;
  }
}

// all 4 weight matrices in one dispatch; grid (1024, 4)
__global__ __launch_bounds__(256) void cvt_w4(const float* __restrict__ w0,
                                              const float* __restrict__ w1,
                                              const float* __restrict__ w2,
                                              const float* __restrict__ w3,
                                              ushort_t* __restrict__ dst)
{
  const float* srcs[4] = {w0, w1, w2, w3};
  const float* s = srcs[blockIdx.y];
  ushort_t* d = dst + (size_t)blockIdx.y * CDIM * CDIM;
  int i = blockIdx.x * 256 + threadIdx.x;
  float4 v = ((const float4*)s)[i];
  ushort4 o;
  o.x = f2bf(v.x); o.y = f2bf(v.y); o.z = f2bf(v.z); o.w = f2bf(v.w);
  ((ushort4*)d)[i] = o;
}

// ---------------- GEMM: Out = A[M,K] @ W[N,K]^T + bias; epilogue variants ----------------
// EPI 0: bf16 row-major   EPI 1: bf16 row-major + RoPE   EPI 2: bf16 transposed [b][ch][tok]   EPI 3: fp32 row-major
template <int EPI>
__global__ __launch_bounds__(256) void gemm_bt(const ushort_t* __restrict__ A,
                                               const ushort_t* __restrict__ W,
                                               const float* __restrict__ bias,
                                               void* __restrict__ OutP,
                                               const float* __restrict__ cosT,
                                               const float* __restrict__ sinT)
{
  __shared__ ushort_t As[128 * 32];
  __shared__ ushort_t Bs[128 * 32];
  const int t = threadIdx.x;
  const int lane = t & 63;
  const int wv = t >> 6;
  const int m0 = blockIdx.y * 128;
  const int n0 = blockIdx.x * 128;
  const int wm = (wv >> 1) * 64;
  const int wn = (wv & 1) * 64;

  f32x4 acc[4][4];
#pragma unroll
  for (int i = 0; i < 4; i++)
#pragma unroll
    for (int j = 0; j < 4; j++) acc[i][j] = (f32x4){0.f, 0.f, 0.f, 0.f};

  const int srow = t >> 2;
  const int scol = (t & 3) * 8;
  const ushort_t* Ag0 = A + (size_t)(m0 + srow) * CDIM + scol;
  const ushort_t* Ag1 = Ag0 + (size_t)64 * CDIM;
  const ushort_t* Wg0 = W + (size_t)(n0 + srow) * CDIM + scol;
  const ushort_t* Wg1 = Wg0 + (size_t)64 * CDIM;
  ushort_t* la0 = &As[srow * 32 + scol];
  ushort_t* la1 = &As[(srow + 64) * 32 + scol];
  ushort_t* lb0 = &Bs[srow * 32 + scol];
  ushort_t* lb1 = &Bs[(srow + 64) * 32 + scol];

  const int fr = lane & 15;
  const int kq = (lane >> 4) * 8;

  for (int kt = 0; kt < CDIM; kt += 32) {
    __syncthreads();
    gld16(la0, Ag0 + kt);
    gld16(la1, Ag1 + kt);
    gld16(lb0, Wg0 + kt);
    gld16(lb1, Wg1 + kt);
    __syncthreads();
    short8 a[4], b[4];
#pragma unroll
    for (int i = 0; i < 4; i++) a[i] = *(const short8*)&As[(wm + i * 16 + fr) * 32 + kq];
#pragma unroll
    for (int i = 0; i < 4; i++) b[i] = *(const short8*)&Bs[(wn + i * 16 + fr) * 32 + kq];
#pragma unroll
    for (int i = 0; i < 4; i++)
#pragma unroll
      for (int j = 0; j < 4; j++)
        acc[i][j] = __builtin_amdgcn_mfma_f32_16x16x32_bf16(a[i], b[j], acc[i][j], 0, 0, 0);
  }

  const int quad = lane >> 4;

  if constexpr (EPI == 1) {
    // RoPE epilogue: pairs (d, d+32) live in (j, j+2) of the same lane.
    ushort_t* Out = (ushort_t*)OutP;
#pragma unroll
    for (int jp = 0; jp < 2; jp++) {
      int n_lo = n0 + wn + jp * 16 + fr;
      int n_hi = n_lo + 32;
      float bl = bias[n_lo], bh = bias[n_hi];
      int d = jp * 16 + fr;              // in-head dim of lo half (0..31)
#pragma unroll
      for (int i = 0; i < 4; i++) {
        int m = m0 + wm + i * 16 + quad * 4;
#pragma unroll
        for (int r = 0; r < 4; r++) {
          int tt = (m + r) & (T_SEQ - 1);
          float c = cosT[tt * HDIM + d];
          float sn = sinT[tt * HDIM + d];
          float lo = acc[i][jp][r] + bl;
          float hi = acc[i][jp + 2][r] + bh;
          Out[(size_t)(m + r) * CDIM + n_lo] = f2bf(lo * c - hi * sn);
          Out[(size_t)(m + r) * CDIM + n_hi] = f2bf(hi * c + lo * sn);
        }
      }
    }
  } else if constexpr (EPI == 2) {
    // transposed output: Vt[b][ch][tok], 4 consecutive tokens per 8B store
    ushort_t* Out = (ushort_t*)OutP;
#pragma unroll
    for (int j = 0; j < 4; j++) {
      int n = n0 + wn + j * 16 + fr;
      float bvv = bias[n];
#pragma unroll
      for (int i = 0; i < 4; i++) {
        int m = m0 + wm + i * 16 + quad * 4;
        int bb = m >> 13;
        int tq = m & (T_SEQ - 1);
        us4 pk;
#pragma unroll
        for (int r = 0; r < 4; r++) pk[r] = f2bf(acc[i][j][r] + bvv);
        *(us4*)&Out[((size_t)bb * CDIM + n) * T_SEQ + tq] = pk;
      }
    }
  } else {
#pragma unroll
    for (int j = 0; j < 4; j++) {
      int n = n0 + wn + j * 16 + fr;
      float bvv = bias[n];
#pragma unroll
      for (int i = 0; i < 4; i++) {
        int m = m0 + wm + i * 16 + quad * 4;
#pragma unroll
        for (int r = 0; r < 4; r++) {
          if constexpr (EPI == 3)
            ((float*)OutP)[(size_t)(m + r) * CDIM + n] = acc[i][j][r] + bvv;
          else
            ((ushort_t*)OutP)[(size_t)(m + r) * CDIM + n] = f2bf(acc[i][j][r] + bvv);
        }
      }
    }
  }
}

// ---------------- windowed attention, flash-style over 8 chunks of 64 keys ----------------
// block: x=head(16), y=w*2+qhalf(64), z=batch(2); 256 threads, wave wv owns q-rows [wv*32, wv*32+32)
// V arrives pre-transposed: Vt[b][ch][tok]. AO may alias Q (per-block exclusive, barrier-ordered).
__global__ __launch_bounds__(256) void attn_kernel(const ushort_t* __restrict__ Q,
                                                   const ushort_t* __restrict__ Kg,
                                                   const ushort_t* __restrict__ Vt,
                                                   const int* __restrict__ mask,
                                                   ushort_t* __restrict__ AO)
{
  __shared__ ushort_t Qs[128 * 72];
  __shared__ ushort_t Ks[64 * 72];
  __shared__ ushort_t Vts[64 * 72];      // [dim][key], vector-written from Vt
  __shared__ ushort_t Ps[4 * 16 * 72];   // per-wave 16-row P staging (swizzled cols)
  __shared__ unsigned char att[512];

  const int t = threadIdx.x;
  const int lane = t & 63;
  const int wv = t >> 6;
  const int h = blockIdx.x;
  const int w = blockIdx.y >> 1;
  const int qh = blockIdx.y & 1;
  const int b = blockIdx.z;

  // attend flags for the window's 512 keys (key j -> pos w*256 + j - 128; pad attends)
  bool a0, a1;
  {
    int p0 = w * 256 + t - 128;
    a0 = (p0 < 0 || p0 >= T_SEQ) ? true : (mask[b * T_SEQ + p0] == 0);
    int p1 = p0 + 256;
    a1 = (p1 < 0 || p1 >= T_SEQ) ? true : (mask[b * T_SEQ + p1] == 0);
  }
  int all1 = __syncthreads_and((int)(a0 && a1));
  att[t] = a0 ? 1 : 0;
  att[t + 256] = a1 ? 1 : 0;
  if (all1 && t == 0) att[0] = 0;   // reference quirk: fully-attendable row masks key 0

  // stage Q tile [128][64] -> Qs (stride 72 = 144B: 16B-aligned rows, bank step 4)
  {
    int row = t >> 3;
    int c8 = (t & 7) * 8;
    size_t qbase = ((size_t)b * T_SEQ + w * 256 + qh * 128) * CDIM + h * HDIM + c8;
#pragma unroll
    for (int p = 0; p < 4; p++) {
      int r = p * 32 + row;
      *(us8*)&Qs[r * 72 + c8] = *(const us8*)&Q[qbase + (size_t)r * CDIM];
    }
  }

  const int fr = lane & 15;
  const int quad = lane >> 4;
  const int kq = quad * 8;
  const ushort_t* vt_base = Vt + ((size_t)b * CDIM + h * HDIM) * T_SEQ;

  float m_run[2][4], l_run[2][4];
  f32x4 o[2][4];
#pragma unroll
  for (int mt = 0; mt < 2; mt++)
#pragma unroll
    for (int r = 0; r < 4; r++) { m_run[mt][r] = -3.0e38f; l_run[mt][r] = 0.f; }
#pragma unroll
  for (int mt = 0; mt < 2; mt++)
#pragma unroll
    for (int nt = 0; nt < 4; nt++) o[mt][nt] = (f32x4){0.f, 0.f, 0.f, 0.f};

  for (int kc = 0; kc < 8; kc++) {
    __syncthreads();  // all waves done reading prior chunk's Ks/Vts
    // stage K chunk [64 keys][64 dims] row-major (vector writes)
    {
      int row = t >> 3;
      int c8 = (t & 7) * 8;
#pragma unroll
      for (int p = 0; p < 2; p++) {
        int jj = p * 32 + row;
        int pos = w * 256 + kc * 64 + jj - 128;
        us8 kval = (us8)(0);
        if (pos >= 0 && pos < T_SEQ)
          kval = *(const us8*)&Kg[((size_t)b * T_SEQ + pos) * CDIM + h * HDIM + c8];
        *(us8*)&Ks[jj * 72 + c8] = kval;
      }
    }
    // stage V chunk [64 dims][64 keys] from pre-transposed Vt (vector writes, no scatter)
    {
      int dd = t >> 3;            // 0..31
      int kg = (t & 7) * 8;       // key group base
      int pos0 = w * 256 + kc * 64 - 128 + kg;   // multiple of 8 -> all-or-nothing
      bool inr = (pos0 >= 0) && (pos0 < T_SEQ);
#pragma unroll
      for (int p = 0; p < 2; p++) {
        int d = p * 32 + dd;
        us8 vv = (us8)(0);
        if (inr) vv = *(const us8*)&vt_base[(size_t)d * T_SEQ + pos0];
        *(us8*)&Vts[d * 72 + kg] = vv;
      }
    }
    __syncthreads();

    // S = Q K^T for this wave's 32 rows x 64 chunk keys
    short8 afr[2][2], bfr[4][2];
#pragma unroll
    for (int mt = 0; mt < 2; mt++)
#pragma unroll
      for (int ks = 0; ks < 2; ks++)
        afr[mt][ks] = *(const short8*)&Qs[(wv * 32 + mt * 16 + fr) * 72 + ks * 32 + kq];
#pragma unroll
    for (int nt = 0; nt < 4; nt++)
#pragma unroll
      for (int ks = 0; ks < 2; ks++)
        bfr[nt][ks] = *(const short8*)&Ks[(nt * 16 + fr) * 72 + ks * 32 + kq];

    f32x4 s[2][4];
#pragma unroll
    for (int mt = 0; mt < 2; mt++)
#pragma unroll
      for (int nt = 0; nt < 4; nt++) {
        f32x4 a = (f32x4){0.f, 0.f, 0.f, 0.f};
        a = __builtin_amdgcn_mfma_f32_16x16x32_bf16(afr[mt][0], bfr[nt][0], a, 0, 0, 0);
        a = __builtin_amdgcn_mfma_f32_16x16x32_bf16(afr[mt][1], bfr[nt][1], a, 0, 0, 0);
        s[mt][nt] = a;
      }

    // scale + mask
    bool at[4];
#pragma unroll
    for (int nt = 0; nt < 4; nt++) at[nt] = att[kc * 64 + nt * 16 + fr] != 0;
#pragma unroll
    for (int mt = 0; mt < 2; mt++)
#pragma unroll
      for (int nt = 0; nt < 4; nt++)
#pragma unroll
        for (int r = 0; r < 4; r++)
          s[mt][nt][r] = at[nt] ? s[mt][nt][r] * 0.125f : -3.0e38f;

    // online softmax (rows live in 16-lane groups)
#pragma unroll
    for (int mt = 0; mt < 2; mt++) {
#pragma unroll
      for (int r = 0; r < 4; r++) {
        float mm = fmaxf(fmaxf(s[mt][0][r], s[mt][1][r]), fmaxf(s[mt][2][r], s[mt][3][r]));
        for (int off = 1; off < 16; off <<= 1) mm = fmaxf(mm, __shfl_xor(mm, off, 64));
        float mnew = fmaxf(m_run[mt][r], mm);
        float alpha = __expf(m_run[mt][r] - mnew);
        float rs = 0.f;
#pragma unroll
        for (int nt = 0; nt < 4; nt++) {
          float p = __expf(s[mt][nt][r] - mnew);
          s[mt][nt][r] = p;
          rs += p;
        }
        for (int off = 1; off < 16; off <<= 1) rs += __shfl_xor(rs, off, 64);
        l_run[mt][r] = l_run[mt][r] * alpha + rs;
        m_run[mt][r] = mnew;
#pragma unroll
        for (int nt = 0; nt < 4; nt++) o[mt][nt][r] *= alpha;
      }
    }

    // V fragments (B-layout) — vector reads from Vts
    short8 vf[4][2];
#pragma unroll
    for (int nt = 0; nt < 4; nt++)
#pragma unroll
      for (int ks = 0; ks < 2; ks++)
        vf[nt][ks] = *(const short8*)&Vts[(nt * 16 + fr) * 72 + ks * 32 + kq];

    // P transform per mt through wave-private Ps (quad-rotation swizzle; no barrier needed)
    ushort_t* pw = &Ps[wv * 16 * 72];
    const int rot_r = 8 * (fr >> 2);
#pragma unroll
    for (int mt = 0; mt < 2; mt++) {
#pragma unroll
      for (int nt = 0; nt < 4; nt++) {
#pragma unroll
        for (int r = 0; r < 4; r++) {
          int cs = ((nt * 16 + fr) + 8 * quad) & 63;     // writer rot = 8*quad
          pw[(quad * 4 + r) * 72 + cs] = f2bf(s[mt][nt][r]);
        }
      }
      short8 pf[2];
#pragma unroll
      for (int ks = 0; ks < 2; ks++)
        pf[ks] = *(const short8*)&pw[fr * 72 + ((ks * 32 + kq + rot_r) & 63)];
#pragma unroll
      for (int nt = 0; nt < 4; nt++) {
        o[mt][nt] = __builtin_amdgcn_mfma_f32_16x16x32_bf16(pf[0], vf[nt][0], o[mt][nt], 0, 0, 0);
        o[mt][nt] = __builtin_amdgcn_mfma_f32_16x16x32_bf16(pf[1], vf[nt][1], o[mt][nt], 0, 0, 0);
      }
    }
  }

  // normalize + store
  size_t obase = ((size_t)b * T_SEQ + w * 256 + qh * 128) * CDIM + h * HDIM;
#pragma unroll
  for (int mt = 0; mt < 2; mt++)
#pragma unroll
    for (int r = 0; r < 4; r++) {
      int row = wv * 32 + mt * 16 + quad * 4 + r;
      float inv = 1.0f / fmaxf(l_run[mt][r], 1e-30f);
#pragma unroll
      for (int nt = 0; nt < 4; nt++) {
        int col = nt * 16 + fr;
        AO[obase + (size_t)row * CDIM + col] = f2bf(o[mt][nt][r] * inv);
      }
    }
}

extern "C" void kernel_launch(void* const* d_in, const int* in_sizes, int n_in,
                              void* d_out, int out_size, void* d_ws, size_t ws_size,
                              hipStream_t stream)
{
  const float* x    = (const float*)d_in[0];
  const int*   pm   = (const int*)d_in[1];
  const float* cosT = (const float*)d_in[2];
  const float* sinT = (const float*)d_in[3];
  const float* Wq   = (const float*)d_in[4];
  const float* bq   = (const float*)d_in[5];
  const float* Wk   = (const float*)d_in[6];
  const float* bk   = (const float*)d_in[7];
  const float* Wv   = (const float*)d_in[8];
  const float* bv   = (const float*)d_in[9];
  const float* Wo   = (const float*)d_in[10];
  const float* bo   = (const float*)d_in[11];
  float* out = (float*)d_out;   // fp32 output, 67.1 MB

  // scratch layout:
  //   d_out lower half : K (bf16)       — dead before final GEMM overwrites d_out
  //   d_out upper half : x_bf (bf16)    — dead after V projection
  //   ws: Wq/Wk/Wv/Wo bf16 (8 MB) + Q (33.5) + Vt (33.5, transposed [b][ch][tok])
  const size_t NTOK = (size_t)B_SZ * T_SEQ;
  const size_t NELT = NTOK * CDIM;
  ushort_t* Kb  = (ushort_t*)d_out;
  ushort_t* xbf = (ushort_t*)d_out + NELT;
  char* ws = (char*)d_ws;
  ushort_t* Wbf = (ushort_t*)ws;                       // 4 x CDIM*CDIM
  ushort_t* Qb  = (ushort_t*)(ws + 4 * (size_t)CDIM * CDIM * 2);
  ushort_t* Vtb = Qb + NELT;
  ushort_t* AO  = Qb;             // AO aliases Q (per-block exclusive)

  cvt_f32_bf16<<<(int)(NELT / 4 / 256), 256, 0, stream>>>(x, xbf, (int)(NELT / 4));
  cvt_w4<<<dim3(CDIM * CDIM / 4 / 256, 4), 256, 0, stream>>>(Wq, Wk, Wv, Wo, Wbf);

  dim3 gg(CDIM / 128, (int)(NTOK / 128));  // (8,128)
  const size_t WSZ = (size_t)CDIM * CDIM;
  gemm_bt<1><<<gg, 256, 0, stream>>>(xbf, Wbf + 0 * WSZ, bq, Qb,  cosT, sinT);  // Q + RoPE
  gemm_bt<1><<<gg, 256, 0, stream>>>(xbf, Wbf + 1 * WSZ, bk, Kb,  cosT, sinT);  // K + RoPE
  gemm_bt<2><<<gg, 256, 0, stream>>>(xbf, Wbf + 2 * WSZ, bv, Vtb, nullptr, nullptr); // V -> Vt

  attn_kernel<<<dim3(NH, NW * 2, B_SZ), 256, 0, stream>>>(Qb, Kb, Vtb, pm, AO);

  gemm_bt<3><<<gg, 256, 0, stream>>>(AO, Wbf + 3 * WSZ, bo, out, nullptr, nullptr);
}

// Round 5
// 451.437 us; speedup vs baseline: 1.2255x; 1.0763x over previous
//
#include <hip/hip_runtime.h>
#include <hip/hip_bf16.h>
#include <stdint.h>

#define T_SEQ 8192
#define B_SZ 2
#define CDIM 1024
#define NH 16
#define HDIM 64
#define NW 32

typedef unsigned short ushort_t;
typedef __attribute__((ext_vector_type(8))) short short8;     // 8 bf16 (4 VGPRs) MFMA A/B frag
typedef __attribute__((ext_vector_type(8))) unsigned short us8;
typedef __attribute__((ext_vector_type(4))) unsigned short us4;
typedef __attribute__((ext_vector_type(4))) float f32x4;      // MFMA C/D frag

__device__ __forceinline__ unsigned short f2bf(float f) {
  union { float f; unsigned int u; } c; c.f = f;
  return (unsigned short)((c.u + 0x7FFFu + ((c.u >> 16) & 1u)) >> 16);
}
__device__ __forceinline__ void gld16(void* lds, const void* g) {
  __builtin_amdgcn_global_load_lds(
      (const __attribute__((address_space(1))) void*)g,
      (__attribute__((address_space(3))) void*)lds, 16, 0, 0);
}

// ---------------- fp32 -> bf16 conversion (RTNE) ----------------
__global__ __launch_bounds__(256) void cvt_f32_bf16(const float* __restrict__ src,
                                                    ushort_t* __restrict__ dst, int n4)
{
  int i = blockIdx.x * 256 + threadIdx.x;
  if (i < n4) {
    float4 v = ((const float4*)src)[i];
    ushort4 o;
    o.x = f2bf(v.x); o.y = f2bf(v.y); o.z = f2bf(v.z); o.w = f2bf(v.w);
    ((ushort4*)dst)[i] = o;
  }
}

// all 4 weight matrices into one contiguous bf16 buffer (rows 0..4095); grid (1024, 4)
__global__ __launch_bounds__(256) void cvt_w4(const float* __restrict__ w0,
                                              const float* __restrict__ w1,
                                              const float* __restrict__ w2,
                                              const float* __restrict__ w3,
                                              ushort_t* __restrict__ dst)
{
  const float* srcs[4] = {w0, w1, w2, w3};
  const float* s = srcs[blockIdx.y];
  ushort_t* d = dst + (size_t)blockIdx.y * CDIM * CDIM;
  int i = blockIdx.x * 256 + threadIdx.x;
  float4 v = ((const float4*)s)[i];
  ushort4 o;
  o.x = f2bf(v.x); o.y = f2bf(v.y); o.z = f2bf(v.z); o.w = f2bf(v.w);
  ((ushort4*)d)[i] = o;
}

// ---------------- shared GEMM core: BK=64, XOR-swizzled LDS, gld16 staging ----------------
// As/Bs: 128 rows x 64 cols bf16 (8 KB each). Logical 16B-block lb at row r lives in
// physical block lb ^ (r&7). Staging: lane l covers row l>>3 (+32/round), phys slot l&7.
__device__ __forceinline__ void gemm_core(const ushort_t* __restrict__ A,
                                          const ushort_t* __restrict__ W,
                                          ushort_t* As, ushort_t* Bs,
                                          int m0, int n0, int t, f32x4 acc[4][4])
{
  const int lane = t & 63;
  const int wv = t >> 6;
  const int wm = (wv >> 1) * 64;
  const int wn = (wv & 1) * 64;
  const int fr = lane & 15;
  const int quad = lane >> 4;

  const int srow = t >> 3;                       // 0..31 (+p*32)
  const int sc8 = ((t & 7) ^ (srow & 7)) * 8;    // swizzled logical col (elems)
  const ushort_t* Ag = A + (size_t)(m0 + srow) * CDIM + sc8;
  const ushort_t* Wg = W + (size_t)(n0 + srow) * CDIM + sc8;
  ushort_t* lA = &As[srow * 64 + (t & 7) * 8];
  ushort_t* lB = &Bs[srow * 64 + (t & 7) * 8];

  for (int kt = 0; kt < CDIM; kt += 64) {
    __syncthreads();
#pragma unroll
    for (int p = 0; p < 4; p++) gld16(lA + p * 2048, Ag + (size_t)p * 32 * CDIM + kt);
#pragma unroll
    for (int p = 0; p < 4; p++) gld16(lB + p * 2048, Wg + (size_t)p * 32 * CDIM + kt);
    __syncthreads();
#pragma unroll
    for (int ks = 0; ks < 2; ks++) {
      short8 a[4], b[4];
#pragma unroll
      for (int i = 0; i < 4; i++)
        a[i] = *(const short8*)&As[(wm + i * 16 + fr) * 64 + (((ks * 4 + quad) ^ (fr & 7)) * 8)];
#pragma unroll
      for (int j = 0; j < 4; j++)
        b[j] = *(const short8*)&Bs[(wn + j * 16 + fr) * 64 + (((ks * 4 + quad) ^ (fr & 7)) * 8)];
#pragma unroll
      for (int i = 0; i < 4; i++)
#pragma unroll
        for (int j = 0; j < 4; j++)
          acc[i][j] = __builtin_amdgcn_mfma_f32_16x16x32_bf16(a[i], b[j], acc[i][j], 0, 0, 0);
    }
  }
}

// ---------------- fused QKV projection: N=3072, per-section epilogue ----------------
// sections (blockIdx.x>>3): 0 -> Q (rope, row-major), 1 -> K (rope, row-major), 2 -> V (transposed [b][ch][tok])
__global__ __launch_bounds__(256, 4) void gemm_qkv(const ushort_t* __restrict__ A,
                                                   const ushort_t* __restrict__ Wcat,
                                                   const float* __restrict__ bq,
                                                   const float* __restrict__ bk,
                                                   const float* __restrict__ bv,
                                                   ushort_t* __restrict__ Qb,
                                                   ushort_t* __restrict__ Kb,
                                                   ushort_t* __restrict__ Vtb,
                                                   const float* __restrict__ cosT,
                                                   const float* __restrict__ sinT)
{
  __shared__ ushort_t SH[17408];          // As(8192) + Bs(8192) in K-loop; 128x136 retile in epilogue
  ushort_t* As = SH;
  ushort_t* Bs = SH + 8192;

  const int t = threadIdx.x;
  const int lane = t & 63;
  const int wv = t >> 6;
  const int wm = (wv >> 1) * 64;
  const int wn = (wv & 1) * 64;
  const int fr = lane & 15;
  const int quad = lane >> 4;
  const int m0 = blockIdx.y * 128;
  const int n0 = blockIdx.x * 128;        // row in Wcat (0..3071)
  const int sec = blockIdx.x >> 3;        // 0=Q 1=K 2=V
  const int nsec0 = (blockIdx.x & 7) * 128;
  const float* bias = (sec == 0) ? bq : (sec == 1) ? bk : bv;

  f32x4 acc[4][4];
#pragma unroll
  for (int i = 0; i < 4; i++)
#pragma unroll
    for (int j = 0; j < 4; j++) acc[i][j] = (f32x4){0.f, 0.f, 0.f, 0.f};

  gemm_core(A, Wcat, As, Bs, m0, n0, t, acc);

  __syncthreads();   // SH reuse guard (all waves done with As/Bs reads)

  if (sec < 2) {
    // RoPE in C-layout regs -> LDS retile (stride 136) -> coalesced us8 stores
    ushort_t* OutQK = sec ? Kb : Qb;
#pragma unroll
    for (int jp = 0; jp < 2; jp++) {
      int d = jp * 16 + fr;                 // head-dim lo (0..31)
      int cl = wn + jp * 16 + fr;           // col in 128-tile
      float bl = bias[nsec0 + cl];
      float bh = bias[nsec0 + cl + 32];
#pragma unroll
      for (int i = 0; i < 4; i++) {
        int rloc = wm + i * 16 + quad * 4;
#pragma unroll
        for (int r = 0; r < 4; r++) {
          int tt = (m0 + rloc + r) & (T_SEQ - 1);
          float c = cosT[tt * HDIM + d];
          float sn = sinT[tt * HDIM + d];
          float lo = acc[i][jp][r] + bl;
          float hi = acc[i][jp + 2][r] + bh;
          SH[(rloc + r) * 136 + cl] = f2bf(lo * c - hi * sn);
          SH[(rloc + r) * 136 + cl + 32] = f2bf(hi * c + lo * sn);
        }
      }
    }
    __syncthreads();
    const int rr0 = t >> 4;                 // 0..15
    const int c8 = (t & 15) * 8;
    size_t gbase = (size_t)m0 * CDIM + nsec0 + c8;
#pragma unroll
    for (int p = 0; p < 8; p++) {
      int rr = p * 16 + rr0;
      *(us8*)&OutQK[gbase + (size_t)rr * CDIM] = *(const us8*)&SH[rr * 136 + c8];
    }
  } else {
    // V -> Vt[b][ch][tok], 4 consecutive tokens per 8B store
#pragma unroll
    for (int j = 0; j < 4; j++) {
      int ch = nsec0 + wn + j * 16 + fr;
      float bvv = bias[ch];
#pragma unroll
      for (int i = 0; i < 4; i++) {
        int m = m0 + wm + i * 16 + quad * 4;
        int bb = m >> 13;
        int tq = m & (T_SEQ - 1);
        us4 pk;
#pragma unroll
        for (int r = 0; r < 4; r++) pk[r] = f2bf(acc[i][j][r] + bvv);
        *(us4*)&Vtb[((size_t)bb * CDIM + ch) * T_SEQ + tq] = pk;
      }
    }
  }
}

// ---------------- output projection: bf16 in, fp32 out ----------------
__global__ __launch_bounds__(256, 4) void gemm_out(const ushort_t* __restrict__ A,
                                                   const ushort_t* __restrict__ W,
                                                   const float* __restrict__ bias,
                                                   float* __restrict__ Out)
{
  __shared__ ushort_t SH[16384];
  ushort_t* As = SH;
  ushort_t* Bs = SH + 8192;

  const int t = threadIdx.x;
  const int lane = t & 63;
  const int wv = t >> 6;
  const int wm = (wv >> 1) * 64;
  const int wn = (wv & 1) * 64;
  const int fr = lane & 15;
  const int quad = lane >> 4;
  const int m0 = blockIdx.y * 128;
  const int n0 = blockIdx.x * 128;

  f32x4 acc[4][4];
#pragma unroll
  for (int i = 0; i < 4; i++)
#pragma unroll
    for (int j = 0; j < 4; j++) acc[i][j] = (f32x4){0.f, 0.f, 0.f, 0.f};

  gemm_core(A, W, As, Bs, m0, n0, t, acc);

#pragma unroll
  for (int j = 0; j < 4; j++) {
    int n = n0 + wn + j * 16 + fr;
    float bvv = bias[n];
#pragma unroll
    for (int i = 0; i < 4; i++) {
      int m = m0 + wm + i * 16 + quad * 4;
#pragma unroll
      for (int r = 0; r < 4; r++)
        Out[(size_t)(m + r) * CDIM + n] = acc[i][j][r] + bvv;
    }
  }
}

// ---------------- windowed attention, flash-style over 8 chunks of 64 keys ----------------
// block: x=head(16), y=w*2+qhalf(64), z=batch(2); 256 threads, wave wv owns q-rows [wv*32, wv*32+32)
// V arrives pre-transposed: Vt[b][ch][tok]. AO may alias Q (per-block exclusive, barrier-ordered).
// Softmax in exp2 domain: s2 = s*(0.125*log2e) + (attend? 0 : -1e38).
__global__ __launch_bounds__(256) void attn_kernel(const ushort_t* __restrict__ Q,
                                                   const ushort_t* __restrict__ Kg,
                                                   const ushort_t* __restrict__ Vt,
                                                   const int* __restrict__ mask,
                                                   ushort_t* __restrict__ AO)
{
  __shared__ ushort_t Qs[128 * 72];
  __shared__ ushort_t Ks[64 * 72];
  __shared__ ushort_t Vts[64 * 72];      // [dim][key]
  __shared__ ushort_t Ps[4 * 16 * 72];   // per-wave 16-row P staging (swizzled cols)
  __shared__ unsigned char att[512];

  const int t = threadIdx.x;
  const int lane = t & 63;
  const int wv = t >> 6;
  const int h = blockIdx.x;
  const int w = blockIdx.y >> 1;
  const int qh = blockIdx.y & 1;
  const int b = blockIdx.z;

  bool a0, a1;
  {
    int p0 = w * 256 + t - 128;
    a0 = (p0 < 0 || p0 >= T_SEQ) ? true : (mask[b * T_SEQ + p0] == 0);
    int p1 = p0 + 256;
    a1 = (p1 < 0 || p1 >= T_SEQ) ? true : (mask[b * T_SEQ + p1] == 0);
  }
  int all1 = __syncthreads_and((int)(a0 && a1));
  att[t] = a0 ? 1 : 0;
  att[t + 256] = a1 ? 1 : 0;
  if (all1 && t == 0) att[0] = 0;   // reference quirk: fully-attendable row masks key 0

  {
    int row = t >> 3;
    int c8 = (t & 7) * 8;
    size_t qbase = ((size_t)b * T_SEQ + w * 256 + qh * 128) * CDIM + h * HDIM + c8;
#pragma unroll
    for (int p = 0; p < 4; p++) {
      int r = p * 32 + row;
      *(us8*)&Qs[r * 72 + c8] = *(const us8*)&Q[qbase + (size_t)r * CDIM];
    }
  }

  const int fr = lane & 15;
  const int quad = lane >> 4;
  const int kq = quad * 8;
  const ushort_t* vt_base = Vt + ((size_t)b * CDIM + h * HDIM) * T_SEQ;
  const float SCL = 0.18033688011112042f;   // 0.125 * log2(e)

  float m_run[2][4], l_run[2][4];
  f32x4 o[2][4];
#pragma unroll
  for (int mt = 0; mt < 2; mt++)
#pragma unroll
    for (int r = 0; r < 4; r++) { m_run[mt][r] = -3.0e38f; l_run[mt][r] = 0.f; }
#pragma unroll
  for (int mt = 0; mt < 2; mt++)
#pragma unroll
    for (int nt = 0; nt < 4; nt++) o[mt][nt] = (f32x4){0.f, 0.f, 0.f, 0.f};

  for (int kc = 0; kc < 8; kc++) {
    __syncthreads();
    {
      int row = t >> 3;
      int c8 = (t & 7) * 8;
#pragma unroll
      for (int p = 0; p < 2; p++) {
        int jj = p * 32 + row;
        int pos = w * 256 + kc * 64 + jj - 128;
        us8 kval = (us8)(0);
        if (pos >= 0 && pos < T_SEQ)
          kval = *(const us8*)&Kg[((size_t)b * T_SEQ + pos) * CDIM + h * HDIM + c8];
        *(us8*)&Ks[jj * 72 + c8] = kval;
      }
    }
    {
      int dd = t >> 3;
      int kg = (t & 7) * 8;
      int pos0 = w * 256 + kc * 64 - 128 + kg;
      bool inr = (pos0 >= 0) && (pos0 < T_SEQ);
#pragma unroll
      for (int p = 0; p < 2; p++) {
        int d = p * 32 + dd;
        us8 vv = (us8)(0);
        if (inr) vv = *(const us8*)&vt_base[(size_t)d * T_SEQ + pos0];
        *(us8*)&Vts[d * 72 + kg] = vv;
      }
    }
    __syncthreads();

    short8 afr[2][2], bfr[4][2];
#pragma unroll
    for (int mt = 0; mt < 2; mt++)
#pragma unroll
      for (int ks = 0; ks < 2; ks++)
        afr[mt][ks] = *(const short8*)&Qs[(wv * 32 + mt * 16 + fr) * 72 + ks * 32 + kq];
#pragma unroll
    for (int nt = 0; nt < 4; nt++)
#pragma unroll
      for (int ks = 0; ks < 2; ks++)
        bfr[nt][ks] = *(const short8*)&Ks[(nt * 16 + fr) * 72 + ks * 32 + kq];

    f32x4 s[2][4];
#pragma unroll
    for (int mt = 0; mt < 2; mt++)
#pragma unroll
      for (int nt = 0; nt < 4; nt++) {
        f32x4 a = (f32x4){0.f, 0.f, 0.f, 0.f};
        a = __builtin_amdgcn_mfma_f32_16x16x32_bf16(afr[mt][0], bfr[nt][0], a, 0, 0, 0);
        a = __builtin_amdgcn_mfma_f32_16x16x32_bf16(afr[mt][1], bfr[nt][1], a, 0, 0, 0);
        s[mt][nt] = a;
      }

    // scale+mask fused into one fma (exp2 domain)
    float kb[4];
#pragma unroll
    for (int nt = 0; nt < 4; nt++)
      kb[nt] = att[kc * 64 + nt * 16 + fr] ? 0.f : -1.0e38f;
#pragma unroll
    for (int mt = 0; mt < 2; mt++)
#pragma unroll
      for (int nt = 0; nt < 4; nt++)
#pragma unroll
        for (int r = 0; r < 4; r++)
          s[mt][nt][r] = __builtin_fmaf(s[mt][nt][r], SCL, kb[nt]);

    // online softmax (base-2)
#pragma unroll
    for (int mt = 0; mt < 2; mt++) {
#pragma unroll
      for (int r = 0; r < 4; r++) {
        float mm = fmaxf(fmaxf(s[mt][0][r], s[mt][1][r]), fmaxf(s[mt][2][r], s[mt][3][r]));
        for (int off = 1; off < 16; off <<= 1) mm = fmaxf(mm, __shfl_xor(mm, off, 64));
        float mnew = fmaxf(m_run[mt][r], mm);
        float alpha = __builtin_amdgcn_exp2f(m_run[mt][r] - mnew);
        float rs = 0.f;
#pragma unroll
        for (int nt = 0; nt < 4; nt++) {
          float p = __builtin_amdgcn_exp2f(s[mt][nt][r] - mnew);
          s[mt][nt][r] = p;
          rs += p;
        }
        for (int off = 1; off < 16; off <<= 1) rs += __shfl_xor(rs, off, 64);
        l_run[mt][r] = l_run[mt][r] * alpha + rs;
        m_run[mt][r] = mnew;
#pragma unroll
        for (int nt = 0; nt < 4; nt++) o[mt][nt][r] *= alpha;
      }
    }

    short8 vf[4][2];
#pragma unroll
    for (int nt = 0; nt < 4; nt++)
#pragma unroll
      for (int ks = 0; ks < 2; ks++)
        vf[nt][ks] = *(const short8*)&Vts[(nt * 16 + fr) * 72 + ks * 32 + kq];

    ushort_t* pw = &Ps[wv * 16 * 72];
    const int rot_r = 8 * (fr >> 2);
#pragma unroll
    for (int mt = 0; mt < 2; mt++) {
#pragma unroll
      for (int nt = 0; nt < 4; nt++) {
#pragma unroll
        for (int r = 0; r < 4; r++) {
          int cs = ((nt * 16 + fr) + 8 * quad) & 63;
          pw[(quad * 4 + r) * 72 + cs] = f2bf(s[mt][nt][r]);
        }
      }
      short8 pf[2];
#pragma unroll
      for (int ks = 0; ks < 2; ks++)
        pf[ks] = *(const short8*)&pw[fr * 72 + ((ks * 32 + kq + rot_r) & 63)];
#pragma unroll
      for (int nt = 0; nt < 4; nt++) {
        o[mt][nt] = __builtin_amdgcn_mfma_f32_16x16x32_bf16(pf[0], vf[nt][0], o[mt][nt], 0, 0, 0);
        o[mt][nt] = __builtin_amdgcn_mfma_f32_16x16x32_bf16(pf[1], vf[nt][1], o[mt][nt], 0, 0, 0);
      }
    }
  }

  size_t obase = ((size_t)b * T_SEQ + w * 256 + qh * 128) * CDIM + h * HDIM;
#pragma unroll
  for (int mt = 0; mt < 2; mt++)
#pragma unroll
    for (int r = 0; r < 4; r++) {
      int row = wv * 32 + mt * 16 + quad * 4 + r;
      float inv = 1.0f / fmaxf(l_run[mt][r], 1e-30f);
#pragma unroll
      for (int nt = 0; nt < 4; nt++) {
        int col = nt * 16 + fr;
        AO[obase + (size_t)row * CDIM + col] = f2bf(o[mt][nt][r] * inv);
      }
    }
}

extern "C" void kernel_launch(void* const* d_in, const int* in_sizes, int n_in,
                              void* d_out, int out_size, void* d_ws, size_t ws_size,
                              hipStream_t stream)
{
  const float* x    = (const float*)d_in[0];
  const int*   pm   = (const int*)d_in[1];
  const float* cosT = (const float*)d_in[2];
  const float* sinT = (const float*)d_in[3];
  const float* Wq   = (const float*)d_in[4];
  const float* bq   = (const float*)d_in[5];
  const float* Wk   = (const float*)d_in[6];
  const float* bk   = (const float*)d_in[7];
  const float* Wv   = (const float*)d_in[8];
  const float* bv   = (const float*)d_in[9];
  const float* Wo   = (const float*)d_in[10];
  const float* bo   = (const float*)d_in[11];
  float* out = (float*)d_out;

  // scratch layout:
  //   d_out lower half : K (bf16)       — dead before final GEMM overwrites d_out
  //   d_out upper half : x_bf (bf16)    — dead after QKV projection
  //   ws: Wcat bf16 [Wq;Wk;Wv;Wo] (8 MB) + Q (33.5) + Vt (33.5, [b][ch][tok])
  const size_t NTOK = (size_t)B_SZ * T_SEQ;
  const size_t NELT = NTOK * CDIM;
  ushort_t* Kb  = (ushort_t*)d_out;
  ushort_t* xbf = (ushort_t*)d_out + NELT;
  char* ws = (char*)d_ws;
  ushort_t* Wbf = (ushort_t*)ws;
  ushort_t* Qb  = (ushort_t*)(ws + 4 * (size_t)CDIM * CDIM * 2);
  ushort_t* Vtb = Qb + NELT;
  ushort_t* AO  = Qb;             // AO aliases Q (per-block exclusive)

  cvt_f32_bf16<<<(int)(NELT / 4 / 256), 256, 0, stream>>>(x, xbf, (int)(NELT / 4));
  cvt_w4<<<dim3(CDIM * CDIM / 4 / 256, 4), 256, 0, stream>>>(Wq, Wk, Wv, Wo, Wbf);

  gemm_qkv<<<dim3(24, (int)(NTOK / 128)), 256, 0, stream>>>(
      xbf, Wbf, bq, bk, bv, Qb, Kb, Vtb, cosT, sinT);

  attn_kernel<<<dim3(NH, NW * 2, B_SZ), 256, 0, stream>>>(Qb, Kb, Vtb, pm, AO);

  gemm_out<<<dim3(8, (int)(NTOK / 128)), 256, 0, stream>>>(
      AO, Wbf + 3 * (size_t)CDIM * CDIM, bo, out);
}